// Round 1
// baseline (11732.734 us; speedup 1.0000x reference)
//
#include <hip/hip_runtime.h>

#define NMODES   64
#define NOFF     2016     // 64*63/2
#define BATCHN   1024
#define NEVAL    200
#define TAYLOR_K 12
#define SQUARINGS 10

// ---------------------------------------------------------------------------
// ws layout (bytes):
//   X    @ 0        : 64*64 double2 = 65536   (X = i*H/2^s)
//   Ta   @ 65536    : 65536                   (ping)
//   Tb   @ 131072   : 65536                   (pong)
//   W    @ 196608   : 64*128 double2 = 131072 (Gauss-Jordan augmented)
//   Binv @ 327680   : 65536
//   T2c  @ 393216   : 64*64 float2 = 32768    (final fp32 T2)
// total 425984 B
// ---------------------------------------------------------------------------

__global__ void build_kernel(const float* __restrict__ params,
                             double2* __restrict__ X, double2* __restrict__ T,
                             double inv2s)
{
    int t = blockIdx.x * 256 + threadIdx.x;
    if (t >= NMODES * NMODES) return;
    int r = t >> 6, c = t & 63;
    double hre, him;
    if (r < c) {
        int idx = r * 63 - (r * (r - 1)) / 2 + (c - r - 1);
        hre = (double)params[idx];
        him = (double)params[NOFF + idx];
    } else if (r > c) {
        int idx = c * 63 - (c * (c - 1)) / 2 + (r - c - 1);
        hre = (double)params[idx];
        him = -(double)params[NOFF + idx];
    } else {
        him = 0.0;
        if (r < 63) {
            hre = (double)params[2 * NOFF + r];
        } else {
            double s = 0.0;
            for (int q = 0; q < 63; ++q) s += (double)params[2 * NOFF + q];
            hre = -s;
        }
    }
    // X = i*H * inv2s  (i*(hre + i*him) = -him + i*hre)
    X[t] = make_double2(-him * inv2s, hre * inv2s);
    T[t] = make_double2((r == c) ? 1.0 : 0.0, 0.0);   // identity seed for Horner
}

// C = alpha*(opA(A) @ B) + beta*I      (complex fp64, 64x64)
__global__ void zmatmul(const double2* __restrict__ A, const double2* __restrict__ Bm,
                        double2* __restrict__ C, double alpha, double beta, int transA)
{
    int t = blockIdx.x * 256 + threadIdx.x;
    if (t >= NMODES * NMODES) return;
    int r = t >> 6, c = t & 63;
    double sr = 0.0, si = 0.0;
    for (int k = 0; k < 64; ++k) {
        double2 av = transA ? A[k * 64 + r] : A[r * 64 + k];  // plain transpose (no conj)
        double2 bv = Bm[k * 64 + c];
        sr += av.x * bv.x - av.y * bv.y;
        si += av.x * bv.y + av.y * bv.x;
    }
    sr *= alpha; si *= alpha;
    if (r == c) sr += beta;
    C[t] = make_double2(sr, si);
}

// Gauss-Jordan with partial pivoting on [I - M + eps*I | I] -> Binv (fp64 complex)
// Single block, 256 threads; W is global scratch 64x128 double2.
__global__ void ge_inverse(const double2* __restrict__ M,
                           double2* __restrict__ W, double2* __restrict__ Binv)
{
    int tid = threadIdx.x;
    __shared__ double2 pivrow_s[128];
    __shared__ double2 piv_f[64];
    __shared__ int piv_idx;

    for (int idx = tid; idx < 64 * 128; idx += 256) {
        int r = idx >> 7, c = idx & 127;
        double2 v;
        if (c < 64) {
            double2 m = M[r * 64 + c];
            v.x = ((r == c) ? (1.0 + 1e-8) : 0.0) - m.x;
            v.y = -m.y;
        } else {
            v.x = ((c - 64) == r) ? 1.0 : 0.0;
            v.y = 0.0;
        }
        W[idx] = v;
    }
    __syncthreads();

    for (int i = 0; i < 64; ++i) {
        // partial pivot: argmax_{r>=i} |W[r][i]|^2 (first wave)
        if (tid < 64) {
            double2 v = W[tid * 128 + i];
            double mag = (tid >= i) ? (v.x * v.x + v.y * v.y) : -1.0;
            int idxr = tid;
            for (int off = 1; off < 64; off <<= 1) {
                double omag = __shfl_xor(mag, off);
                int oidx = __shfl_xor(idxr, off);
                if (omag > mag) { mag = omag; idxr = oidx; }
            }
            if (tid == 0) piv_idx = idxr;
        }
        __syncthreads();
        int p = piv_idx;
        double2 pe = W[p * 128 + i];
        double den = pe.x * pe.x + pe.y * pe.y;
        double ipr = pe.x / den, ipi = -pe.y / den;
        __syncthreads();   // everyone has read pe before rows get modified
        if (tid < 128) {
            int c = tid;
            double2 wi = W[i * 128 + c];
            double2 wp = W[p * 128 + c];
            double2 nr;
            nr.x = wp.x * ipr - wp.y * ipi;
            nr.y = wp.x * ipi + wp.y * ipr;
            W[i * 128 + c] = nr;
            if (p != i) W[p * 128 + c] = wi;
            pivrow_s[c] = nr;
        }
        __syncthreads();
        if (tid < 64) piv_f[tid] = W[tid * 128 + i];
        __syncthreads();
        for (int idx = tid; idx < 64 * 128; idx += 256) {
            int r = idx >> 7, c = idx & 127;
            if (r == i) continue;
            double2 f = piv_f[r];
            double2 pr = pivrow_s[c];
            double2 w = W[idx];
            w.x -= f.x * pr.x - f.y * pr.y;
            w.y -= f.x * pr.y + f.y * pr.x;
            W[idx] = w;
        }
        __syncthreads();
    }
    for (int idx = tid; idx < 64 * 64; idx += 256) {
        int r = idx >> 6, c = idx & 63;
        Binv[idx] = W[r * 128 + 64 + c];
    }
}

// T2[r,c] = -kappa[c] * ( P[r,c] + 0.5*delta_rc )   (column scaling per numpy broadcast!)
__global__ void t2_build(const double2* __restrict__ P, const float* __restrict__ kappa,
                         float2* __restrict__ T2c)
{
    int t = blockIdx.x * 256 + threadIdx.x;
    if (t >= NMODES * NMODES) return;
    int r = t >> 6, c = t & 63;
    double2 p = P[t];
    double kc = (double)kappa[c];
    T2c[t] = make_float2((float)(-kc * (p.x + ((r == c) ? 0.5 : 0.0))),
                         (float)(-kc * p.y));
}

// ---------------------------------------------------------------------------
// ODE: one batch element per 64-lane wave; lane j = mode j.
// T2 row j in registers (128 VGPRs); state broadcast via 512B LDS buffers.
// Per-block adaptive Dormand-Prince (FSAL), stepping exactly onto eval times.
// ---------------------------------------------------------------------------
#define RHS(BUF, YR, YI, KR, KI) do {                                   \
    sA[BUF][j] = make_float2((YR), (YI));                               \
    __syncthreads();                                                    \
    float a0 = 0.f, a1 = 0.f, a2 = 0.f, a3 = 0.f;                       \
    _Pragma("unroll")                                                   \
    for (int kk = 0; kk < 64; ++kk) {                                   \
        float2 av = sA[BUF][kk];                                        \
        a0 = fmaf(t2r[kk], av.x, a0);                                   \
        a1 = fmaf(t2i[kk], av.y, a1);                                   \
        a2 = fmaf(t2r[kk], av.y, a2);                                   \
        a3 = fmaf(t2i[kk], av.x, a3);                                   \
    }                                                                   \
    float fq = fmaf(nlj, fmaf((YR), (YR), (YI) * (YI)), om);            \
    (KR) = a0 - a1 - fq * (YI);                                         \
    (KI) = a2 + a3 + fq * (YR);                                         \
} while (0)

__global__ void __launch_bounds__(64, 1)
ode_kernel(const float* __restrict__ A0, const float2* __restrict__ T2c,
           const float* __restrict__ omega, const float* __restrict__ nonlin,
           float2* __restrict__ out)
{
    const int b = blockIdx.x;
    const int j = threadIdx.x;
    __shared__ float2 sA[2][64];

    float t2r[64], t2i[64];
    const float4* T2v = (const float4*)(T2c + j * 64);
#pragma unroll
    for (int k = 0; k < 32; ++k) {
        float4 v = T2v[k];
        t2r[2 * k]     = v.x; t2i[2 * k]     = v.y;
        t2r[2 * k + 1] = v.z; t2i[2 * k + 1] = v.w;
    }

    const float om  = omega[j];
    const float nlj = nonlin[j];

    float yre, yim;
    if (j < 48) {
        yre = A0[(b * 48 + j) * 2 + 0];
        yim = A0[(b * 48 + j) * 2 + 1];
    } else {
        yre = 1.0f; yim = 0.0f;
    }

    out[(size_t)b * 64 + j] = make_float2(yre, yim);   // t = 0

    // Dormand-Prince coefficients
    const float A21 = 0.2f;
    const float A31 = 3.0f/40.0f, A32 = 9.0f/40.0f;
    const float A41 = 44.0f/45.0f, A42 = -56.0f/15.0f, A43 = 32.0f/9.0f;
    const float A51 = 19372.0f/6561.0f, A52 = -25360.0f/2187.0f,
                A53 = 64448.0f/6561.0f, A54 = -212.0f/729.0f;
    const float A61 = 9017.0f/3168.0f, A62 = -355.0f/33.0f,
                A63 = 46732.0f/5247.0f, A64 = 49.0f/176.0f, A65 = -5103.0f/18656.0f;
    const float B1 = 35.0f/384.0f, B3 = 500.0f/1113.0f, B4 = 125.0f/192.0f,
                B5 = -2187.0f/6784.0f, B6 = 11.0f/84.0f;
    const float E1 = (float)(35.0/384.0 - 5179.0/57600.0);
    const float E3 = (float)(500.0/1113.0 - 7571.0/16695.0);
    const float E4 = (float)(125.0/192.0 - 393.0/640.0);
    const float E5 = (float)(-2187.0/6784.0 + 92097.0/339200.0);
    const float E6 = (float)(11.0/84.0 - 187.0/2100.0);
    const float E7 = (float)(-1.0/40.0);

    float k1r, k1i, k2r, k2i, k3r, k3i, k4r, k4i, k5r, k5i, k6r, k6i, k7r, k7i;

    RHS(0, yre, yim, k1r, k1i);   // FSAL seed

    float h = 3e-4f;
    const float DT = (float)(2.0 / 199.0);
    const float RTOL = 1e-6f, ATOL = 1e-9f;

    for (int i = 1; i < NEVAL; ++i) {
        float rem = DT;
        while (rem > 0.0f) {
            float hh = fminf(h, rem);

            float y2r = fmaf(hh * A21, k1r, yre);
            float y2i = fmaf(hh * A21, k1i, yim);
            RHS(1, y2r, y2i, k2r, k2i);

            float y3r = yre + hh * (A31 * k1r + A32 * k2r);
            float y3i = yim + hh * (A31 * k1i + A32 * k2i);
            RHS(0, y3r, y3i, k3r, k3i);

            float y4r = yre + hh * (A41 * k1r + A42 * k2r + A43 * k3r);
            float y4i = yim + hh * (A41 * k1i + A42 * k2i + A43 * k3i);
            RHS(1, y4r, y4i, k4r, k4i);

            float y5r = yre + hh * (A51 * k1r + A52 * k2r + A53 * k3r + A54 * k4r);
            float y5i = yim + hh * (A51 * k1i + A52 * k2i + A53 * k3i + A54 * k4i);
            RHS(0, y5r, y5i, k5r, k5i);

            float y6r = yre + hh * (A61 * k1r + A62 * k2r + A63 * k3r + A64 * k4r + A65 * k5r);
            float y6i = yim + hh * (A61 * k1i + A62 * k2i + A63 * k3i + A64 * k4i + A65 * k5i);
            RHS(1, y6r, y6i, k6r, k6i);

            float ynr = yre + hh * (B1 * k1r + B3 * k3r + B4 * k4r + B5 * k5r + B6 * k6r);
            float yni = yim + hh * (B1 * k1i + B3 * k3i + B4 * k4i + B5 * k5i + B6 * k6i);
            RHS(0, ynr, yni, k7r, k7i);

            float er = hh * (E1 * k1r + E3 * k3r + E4 * k4r + E5 * k5r + E6 * k6r + E7 * k7r);
            float ei = hh * (E1 * k1i + E3 * k3i + E4 * k4i + E5 * k5i + E6 * k6i + E7 * k7i);

            float s0 = fmaf(RTOL, fmaxf(fabsf(yre), fabsf(ynr)), ATOL);
            float s1 = fmaf(RTOL, fmaxf(fabsf(yim), fabsf(yni)), ATOL);
            float q0 = er / s0, q1 = ei / s1;
            float rr = q0 * q0 + q1 * q1;
#pragma unroll
            for (int off = 1; off < 64; off <<= 1) rr += __shfl_xor(rr, off);
            float msq = rr * (1.0f / 128.0f);

            bool accept = (msq <= 1.0f) || (hh <= 1e-6f);
            float rn  = sqrtf(fmaxf(msq, 1e-16f));
            float fac = 0.9f * __powf(rn, -0.2f);
            fac = fminf(fmaxf(fac, 0.2f), 10.0f);
            float hnew = hh * fac;
            if (accept) {
                yre = ynr; yim = yni;
                k1r = k7r; k1i = k7i;       // FSAL
                rem -= hh;
                if (hh < h) hnew = fmaxf(hnew, h);   // don't shrink due to boundary clamp
            }
            h = hnew;
        }
        out[((size_t)i * BATCHN + b) * 64 + j] = make_float2(yre, yim);
    }
}

extern "C" void kernel_launch(void* const* d_in, const int* in_sizes, int n_in,
                              void* d_out, int out_size, void* d_ws, size_t ws_size,
                              hipStream_t stream)
{
    const float* A0     = (const float*)d_in[0];
    const float* params = (const float*)d_in[1];
    const float* omega  = (const float*)d_in[2];
    const float* kappa  = (const float*)d_in[3];
    const float* nonlin = (const float*)d_in[4];
    float2* out = (float2*)d_out;

    char* ws = (char*)d_ws;
    double2* X    = (double2*)(ws + 0);
    double2* Ta   = (double2*)(ws + 65536);
    double2* Tb   = (double2*)(ws + 131072);
    double2* W    = (double2*)(ws + 196608);
    double2* Binv = (double2*)(ws + 327680);
    float2*  T2c  = (float2*)(ws + 393216);

    // X = i*H / 2^10 ; Ta = I
    build_kernel<<<16, 256, 0, stream>>>(params, X, Ta, 1.0 / 1024.0);

    // Horner Taylor: T <- I + (1/k) X T,  k = K..1
    double2* cur = Ta; double2* nxt = Tb;
    for (int k = TAYLOR_K; k >= 1; --k) {
        zmatmul<<<16, 256, 0, stream>>>(X, cur, nxt, 1.0 / (double)k, 1.0, 0);
        double2* tmp = cur; cur = nxt; nxt = tmp;
    }
    // squarings: U = T^(2^10)
    for (int q = 0; q < SQUARINGS; ++q) {
        zmatmul<<<16, 256, 0, stream>>>(cur, cur, nxt, 1.0, 0.0, 0);
        double2* tmp = cur; cur = nxt; nxt = tmp;
    }
    // M = U^T U  (plain transpose)
    zmatmul<<<16, 256, 0, stream>>>(cur, cur, nxt, 1.0, 0.0, 1);
    // Binv = (I - M + eps I)^-1
    ge_inverse<<<1, 256, 0, stream>>>(nxt, W, Binv);
    // P = M * Binv  -> cur
    zmatmul<<<16, 256, 0, stream>>>(nxt, Binv, cur, 1.0, 0.0, 0);
    // T2 = -kappa ∘ (0.5 I + P)   (fp32)
    t2_build<<<16, 256, 0, stream>>>(cur, kappa, T2c);

    // integrate
    ode_kernel<<<BATCHN, 64, 0, stream>>>(A0, T2c, omega, nonlin, out);
}

// Round 2
// 4898.382 us; speedup vs baseline: 2.3952x; 2.3952x over previous
//
#include <hip/hip_runtime.h>

#define NMODES   64
#define NOFF     2016     // 64*63/2
#define BATCHN   1024
#define NEVAL    200
#define TAYLOR_K 12
#define SQUARINGS 10

typedef float v2f __attribute__((ext_vector_type(2)));

// ---------------------------------------------------------------------------
// ws layout (bytes):
//   X    @ 0        : 64*64 double2 = 65536   (X = i*H/2^s)
//   Ta   @ 65536    : 65536                   (ping)
//   Tb   @ 131072   : 65536                   (pong)
//   W    @ 196608   : 64*128 double2 = 131072 (Gauss-Jordan augmented)
//   Binv @ 327680   : 65536
//   T2c  @ 393216   : 64*64 float2 = 32768    (final fp32 T2)
// ---------------------------------------------------------------------------

__global__ void build_kernel(const float* __restrict__ params,
                             double2* __restrict__ X, double2* __restrict__ T,
                             double inv2s)
{
    int t = blockIdx.x * 256 + threadIdx.x;
    if (t >= NMODES * NMODES) return;
    int r = t >> 6, c = t & 63;
    double hre, him;
    if (r < c) {
        int idx = r * 63 - (r * (r - 1)) / 2 + (c - r - 1);
        hre = (double)params[idx];
        him = (double)params[NOFF + idx];
    } else if (r > c) {
        int idx = c * 63 - (c * (c - 1)) / 2 + (r - c - 1);
        hre = (double)params[idx];
        him = -(double)params[NOFF + idx];
    } else {
        him = 0.0;
        if (r < 63) {
            hre = (double)params[2 * NOFF + r];
        } else {
            double s = 0.0;
            for (int q = 0; q < 63; ++q) s += (double)params[2 * NOFF + q];
            hre = -s;
        }
    }
    X[t] = make_double2(-him * inv2s, hre * inv2s);
    T[t] = make_double2((r == c) ? 1.0 : 0.0, 0.0);
}

__global__ void zmatmul(const double2* __restrict__ A, const double2* __restrict__ Bm,
                        double2* __restrict__ C, double alpha, double beta, int transA)
{
    int t = blockIdx.x * 256 + threadIdx.x;
    if (t >= NMODES * NMODES) return;
    int r = t >> 6, c = t & 63;
    double sr = 0.0, si = 0.0;
    for (int k = 0; k < 64; ++k) {
        double2 av = transA ? A[k * 64 + r] : A[r * 64 + k];
        double2 bv = Bm[k * 64 + c];
        sr += av.x * bv.x - av.y * bv.y;
        si += av.x * bv.y + av.y * bv.x;
    }
    sr *= alpha; si *= alpha;
    if (r == c) sr += beta;
    C[t] = make_double2(sr, si);
}

__global__ void ge_inverse(const double2* __restrict__ M,
                           double2* __restrict__ W, double2* __restrict__ Binv)
{
    int tid = threadIdx.x;
    __shared__ double2 pivrow_s[128];
    __shared__ double2 piv_f[64];
    __shared__ int piv_idx;

    for (int idx = tid; idx < 64 * 128; idx += 256) {
        int r = idx >> 7, c = idx & 127;
        double2 v;
        if (c < 64) {
            double2 m = M[r * 64 + c];
            v.x = ((r == c) ? (1.0 + 1e-8) : 0.0) - m.x;
            v.y = -m.y;
        } else {
            v.x = ((c - 64) == r) ? 1.0 : 0.0;
            v.y = 0.0;
        }
        W[idx] = v;
    }
    __syncthreads();

    for (int i = 0; i < 64; ++i) {
        if (tid < 64) {
            double2 v = W[tid * 128 + i];
            double mag = (tid >= i) ? (v.x * v.x + v.y * v.y) : -1.0;
            int idxr = tid;
            for (int off = 1; off < 64; off <<= 1) {
                double omag = __shfl_xor(mag, off);
                int oidx = __shfl_xor(idxr, off);
                if (omag > mag) { mag = omag; idxr = oidx; }
            }
            if (tid == 0) piv_idx = idxr;
        }
        __syncthreads();
        int p = piv_idx;
        double2 pe = W[p * 128 + i];
        double den = pe.x * pe.x + pe.y * pe.y;
        double ipr = pe.x / den, ipi = -pe.y / den;
        __syncthreads();
        if (tid < 128) {
            int c = tid;
            double2 wi = W[i * 128 + c];
            double2 wp = W[p * 128 + c];
            double2 nr;
            nr.x = wp.x * ipr - wp.y * ipi;
            nr.y = wp.x * ipi + wp.y * ipr;
            W[i * 128 + c] = nr;
            if (p != i) W[p * 128 + c] = wi;
            pivrow_s[c] = nr;
        }
        __syncthreads();
        if (tid < 64) piv_f[tid] = W[tid * 128 + i];
        __syncthreads();
        for (int idx = tid; idx < 64 * 128; idx += 256) {
            int r = idx >> 7, c = idx & 127;
            if (r == i) continue;
            double2 f = piv_f[r];
            double2 pr = pivrow_s[c];
            double2 w = W[idx];
            w.x -= f.x * pr.x - f.y * pr.y;
            w.y -= f.x * pr.y + f.y * pr.x;
            W[idx] = w;
        }
        __syncthreads();
    }
    for (int idx = tid; idx < 64 * 64; idx += 256) {
        int r = idx >> 6, c = idx & 63;
        Binv[idx] = W[r * 128 + 64 + c];
    }
}

__global__ void t2_build(const double2* __restrict__ P, const float* __restrict__ kappa,
                         float2* __restrict__ T2c)
{
    int t = blockIdx.x * 256 + threadIdx.x;
    if (t >= NMODES * NMODES) return;
    int r = t >> 6, c = t & 63;
    double2 p = P[t];
    double kc = (double)kappa[c];
    T2c[t] = make_float2((float)(-kc * (p.x + ((r == c) ? 0.5 : 0.0))),
                         (float)(-kc * p.y));
}

// ---------------------------------------------------------------------------
// ODE kernel: one batch element per 64-lane wave, mode j = lane j.
// No LDS, no barriers. Broadcast via v_readlane -> SGPR consumed by FMA.
// T2 row in 128 VGPRs as float2 pairs (v_pk_fma_f32 candidates).
// ---------------------------------------------------------------------------

__device__ __forceinline__ v2f vfma(float c, v2f a, v2f b) {
    v2f cc = {c, c};
    return __builtin_elementwise_fma(cc, a, b);
}
__device__ __forceinline__ v2f vscale(float c, v2f a) {
    v2f cc = {c, c};
    return cc * a;
}

// full-wave (64-lane) sum via DPP, result broadcast through SGPR
__device__ __forceinline__ float wave_sum64(float x) {
    x += __int_as_float(__builtin_amdgcn_update_dpp(0, __float_as_int(x), 0x111, 0xf, 0xf, false)); // row_shr:1
    x += __int_as_float(__builtin_amdgcn_update_dpp(0, __float_as_int(x), 0x112, 0xf, 0xf, false)); // row_shr:2
    x += __int_as_float(__builtin_amdgcn_update_dpp(0, __float_as_int(x), 0x114, 0xf, 0xf, false)); // row_shr:4
    x += __int_as_float(__builtin_amdgcn_update_dpp(0, __float_as_int(x), 0x118, 0xf, 0xf, false)); // row_shr:8
    x += __int_as_float(__builtin_amdgcn_update_dpp(0, __float_as_int(x), 0x142, 0xa, 0xf, false)); // row_bcast:15
    x += __int_as_float(__builtin_amdgcn_update_dpp(0, __float_as_int(x), 0x143, 0xc, 0xf, false)); // row_bcast:31
    return __int_as_float(__builtin_amdgcn_readlane(__float_as_int(x), 63));
}

// K = (T2 @ Y) + i*(om + nl*|Y|^2)*Y   via readlane broadcast
#define RHS(Yv, Kv) do {                                                          \
    v2f P = {0.f, 0.f}, Q = {0.f, 0.f};                                           \
    _Pragma("unroll")                                                             \
    for (int kk = 0; kk < 64; ++kk) {                                             \
        float br = __int_as_float(__builtin_amdgcn_readlane(__float_as_int((Yv).x), kk)); \
        float bi = __int_as_float(__builtin_amdgcn_readlane(__float_as_int((Yv).y), kk)); \
        v2f t2p = t2c[kk];                                                        \
        v2f brv = {br, br};                                                       \
        v2f biv = {bi, bi};                                                       \
        P = __builtin_elementwise_fma(brv, t2p, P);                               \
        Q = __builtin_elementwise_fma(biv, t2p, Q);                               \
    }                                                                             \
    float fq = fmaf(nlj, fmaf((Yv).x, (Yv).x, (Yv).y * (Yv).y), om);              \
    (Kv).x = P.x - Q.y - fq * (Yv).y;                                             \
    (Kv).y = P.y + Q.x + fq * (Yv).x;                                             \
} while (0)

__global__ void __launch_bounds__(64, 1)
ode_kernel(const float* __restrict__ A0, const float2* __restrict__ T2c,
           const float* __restrict__ omega, const float* __restrict__ nonlin,
           float2* __restrict__ out)
{
    const int b = blockIdx.x;
    const int j = threadIdx.x;

    v2f t2c[64];
    const float4* T2v = (const float4*)(T2c + j * 64);
#pragma unroll
    for (int k = 0; k < 32; ++k) {
        float4 v = T2v[k];
        t2c[2 * k]     = (v2f){v.x, v.y};
        t2c[2 * k + 1] = (v2f){v.z, v.w};
    }

    const float om  = omega[j];
    const float nlj = nonlin[j];

    v2f Y;
    if (j < 48) {
        Y.x = A0[(b * 48 + j) * 2 + 0];
        Y.y = A0[(b * 48 + j) * 2 + 1];
    } else {
        Y.x = 1.0f; Y.y = 0.0f;
    }

    out[(size_t)b * 64 + j] = make_float2(Y.x, Y.y);   // t = 0

    const float A21 = 0.2f;
    const float A31 = 3.0f/40.0f, A32 = 9.0f/40.0f;
    const float A41 = 44.0f/45.0f, A42 = -56.0f/15.0f, A43 = 32.0f/9.0f;
    const float A51 = 19372.0f/6561.0f, A52 = -25360.0f/2187.0f,
                A53 = 64448.0f/6561.0f, A54 = -212.0f/729.0f;
    const float A61 = 9017.0f/3168.0f, A62 = -355.0f/33.0f,
                A63 = 46732.0f/5247.0f, A64 = 49.0f/176.0f, A65 = -5103.0f/18656.0f;
    const float B1 = 35.0f/384.0f, B3 = 500.0f/1113.0f, B4 = 125.0f/192.0f,
                B5 = -2187.0f/6784.0f, B6 = 11.0f/84.0f;
    const float E1 = (float)(35.0/384.0 - 5179.0/57600.0);
    const float E3 = (float)(500.0/1113.0 - 7571.0/16695.0);
    const float E4 = (float)(125.0/192.0 - 393.0/640.0);
    const float E5 = (float)(-2187.0/6784.0 + 92097.0/339200.0);
    const float E6 = (float)(11.0/84.0 - 187.0/2100.0);
    const float E7 = (float)(-1.0/40.0);

    v2f K1, K2, K3, K4, K5, K6, K7;

    RHS(Y, K1);   // FSAL seed

    float h = 3e-4f;
    const float DT = (float)(2.0 / 199.0);
    const float RTOL = 1e-6f, ATOL = 1e-9f;

    for (int i = 1; i < NEVAL; ++i) {
        float rem = DT;
        while (rem > 0.0f) {
            float hh = fminf(h, rem);

            v2f y2 = vfma(hh * A21, K1, Y);
            RHS(y2, K2);

            v2f s3 = vfma(A32, K2, vscale(A31, K1));
            v2f y3 = vfma(hh, s3, Y);
            RHS(y3, K3);

            v2f s4 = vfma(A43, K3, vfma(A42, K2, vscale(A41, K1)));
            v2f y4 = vfma(hh, s4, Y);
            RHS(y4, K4);

            v2f s5 = vfma(A54, K4, vfma(A53, K3, vfma(A52, K2, vscale(A51, K1))));
            v2f y5 = vfma(hh, s5, Y);
            RHS(y5, K5);

            v2f s6 = vfma(A65, K5, vfma(A64, K4, vfma(A63, K3, vfma(A62, K2, vscale(A61, K1)))));
            v2f y6 = vfma(hh, s6, Y);
            RHS(y6, K6);

            v2f sn = vfma(B6, K6, vfma(B5, K5, vfma(B4, K4, vfma(B3, K3, vscale(B1, K1)))));
            v2f Yn = vfma(hh, sn, Y);
            RHS(Yn, K7);

            v2f se = vfma(E7, K7, vfma(E6, K6, vfma(E5, K5, vfma(E4, K4, vfma(E3, K3, vscale(E1, K1))))));
            v2f E = vscale(hh, se);

            float s0 = fmaf(RTOL, fmaxf(fabsf(Y.x), fabsf(Yn.x)), ATOL);
            float s1 = fmaf(RTOL, fmaxf(fabsf(Y.y), fabsf(Yn.y)), ATOL);
            float q0 = E.x / s0, q1 = E.y / s1;
            float rr = fmaf(q0, q0, q1 * q1);
            float tot = wave_sum64(rr);
            float msq = tot * (1.0f / 128.0f);

            bool accept = (msq <= 1.0f) || (hh <= 1e-6f);
            float rn  = sqrtf(fmaxf(msq, 1e-16f));
            float fac = 0.9f * __powf(rn, -0.2f);
            fac = fminf(fmaxf(fac, 0.2f), 10.0f);
            float hnew = hh * fac;
            if (accept) {
                Y = Yn;
                K1 = K7;                       // FSAL
                rem -= hh;
                if (hh < h) hnew = fmaxf(hnew, h);   // boundary clamp shouldn't shrink h
            }
            h = hnew;
        }
        out[((size_t)i * BATCHN + b) * 64 + j] = make_float2(Y.x, Y.y);
    }
}

extern "C" void kernel_launch(void* const* d_in, const int* in_sizes, int n_in,
                              void* d_out, int out_size, void* d_ws, size_t ws_size,
                              hipStream_t stream)
{
    const float* A0     = (const float*)d_in[0];
    const float* params = (const float*)d_in[1];
    const float* omega  = (const float*)d_in[2];
    const float* kappa  = (const float*)d_in[3];
    const float* nonlin = (const float*)d_in[4];
    float2* out = (float2*)d_out;

    char* ws = (char*)d_ws;
    double2* X    = (double2*)(ws + 0);
    double2* Ta   = (double2*)(ws + 65536);
    double2* Tb   = (double2*)(ws + 131072);
    double2* W    = (double2*)(ws + 196608);
    double2* Binv = (double2*)(ws + 327680);
    float2*  T2c  = (float2*)(ws + 393216);

    build_kernel<<<16, 256, 0, stream>>>(params, X, Ta, 1.0 / 1024.0);

    double2* cur = Ta; double2* nxt = Tb;
    for (int k = TAYLOR_K; k >= 1; --k) {
        zmatmul<<<16, 256, 0, stream>>>(X, cur, nxt, 1.0 / (double)k, 1.0, 0);
        double2* tmp = cur; cur = nxt; nxt = tmp;
    }
    for (int q = 0; q < SQUARINGS; ++q) {
        zmatmul<<<16, 256, 0, stream>>>(cur, cur, nxt, 1.0, 0.0, 0);
        double2* tmp = cur; cur = nxt; nxt = tmp;
    }
    zmatmul<<<16, 256, 0, stream>>>(cur, cur, nxt, 1.0, 0.0, 1);   // M = U^T U
    ge_inverse<<<1, 256, 0, stream>>>(nxt, W, Binv);
    zmatmul<<<16, 256, 0, stream>>>(nxt, Binv, cur, 1.0, 0.0, 0);  // P = M * Binv
    t2_build<<<16, 256, 0, stream>>>(cur, kappa, T2c);

    ode_kernel<<<BATCHN, 64, 0, stream>>>(A0, T2c, omega, nonlin, out);
}